// Round 6
// baseline (203.119 us; speedup 1.0000x reference)
//
#include <hip/hip_runtime.h>
#include <math.h>

#define INO 128
#define INN 128
#define HID 64
#define NB  512
#define NN  2048
#define TB  4            // b-rows per block
#define NCH 8            // n-chunks
#define NPC (NN / NCH)   // 256 n per chunk

// pre[row][h], rows [0,512)=xo@W1[:128]+b1, rows [512,2560)=xn@W1[128:].
__global__ __launch_bounds__(256) void pre_kernel(
    const float* __restrict__ xo, const float* __restrict__ xn,
    const float* __restrict__ W1, const float* __restrict__ b1,
    float* __restrict__ pre)
{
    int t = blockIdx.x * blockDim.x + threadIdx.x;
    int row = t >> 6;
    int h = t & 63;
    if (row >= NB + NN) return;
    const float* x;
    const float* w;
    float a0, a1 = 0.f, a2 = 0.f, a3 = 0.f;
    if (row < NB) { x = xo + row * INO;        w = W1;             a0 = b1[h]; }
    else          { x = xn + (row - NB) * INN; w = W1 + INO * HID; a0 = 0.f;  }
    const float4* x4 = (const float4*)x;
#pragma unroll
    for (int k4 = 0; k4 < INO / 4; ++k4) {
        float4 xv = x4[k4];
        int kb = k4 * 4;
        a0 = fmaf(xv.x, w[(kb + 0) * HID + h], a0);
        a1 = fmaf(xv.y, w[(kb + 1) * HID + h], a1);
        a2 = fmaf(xv.z, w[(kb + 2) * HID + h], a2);
        a3 = fmaf(xv.w, w[(kb + 3) * HID + h], a3);
    }
    pre[row * HID + h] = (a0 + a1) + (a2 + a3);
}

// One block per (b-tile of 4) x (n-chunk of 256): scores, local softmax
// stats, PV partials. Low-register variant: 1 n per thread in score phase,
// 1 column per thread in PV phase. __launch_bounds__(256,4) caps VGPR at 128
// so 4 blocks/CU are co-resident (1024 blocks total = 4/CU).
__global__ __launch_bounds__(256, 4) void score_pv_kernel(
    const float* __restrict__ pre, const float* __restrict__ xn,
    const float* __restrict__ W2,
    float* __restrict__ smax, float* __restrict__ ssum,
    float* __restrict__ part)
{
    const int bt = blockIdx.x >> 3;     // 0..127
    const int ch = blockIdx.x & 7;      // 0..7
    const int b0 = bt * TB;
    const int n0 = ch * NPC;
    const int tid = threadIdx.x;
    const int lane = tid & 63, wid = tid >> 6;

    __shared__ float  s_po[TB][HID];       // 1 KB
    __shared__ float  s_w2[HID];           // 256 B
    __shared__ float4 s_p4[NPC];           // 4 KB: p[n_local] for 4 b's
    __shared__ float  s_red[4][2 * TB];    // per-wave max / sum
    __shared__ float  s_part[2][TB][INN];  // 4 KB: PV partials (2 n-groups)

    const float* pre_n = pre + NB * HID;
    s_po[tid >> 6][tid & 63] = pre[(b0 + (tid >> 6)) * HID + (tid & 63)];
    if (tid < HID) s_w2[tid] = W2[tid];
    __syncthreads();

    // ---- scores: thread owns n_local = tid, all 4 b's ----
    float acc[TB] = {0.f, 0.f, 0.f, 0.f};
    const float4* pn = (const float4*)(pre_n + (n0 + tid) * HID);
#pragma unroll
    for (int j = 0; j < HID / 4; ++j) {
        float4 v = pn[j];
#pragma unroll
        for (int hh = 0; hh < 4; ++hh) {
            float w = s_w2[4 * j + hh];
            float e = (&v.x)[hh];
#pragma unroll
            for (int b = 0; b < TB; ++b) {
                float t = s_po[b][4 * j + hh] + e;
                acc[b] = fmaf(fmaxf(t, 0.2f * t), w, acc[b]);
            }
        }
    }

    // ---- per-b chunk max ----
    float m[TB];
#pragma unroll
    for (int b = 0; b < TB; ++b) {
        float v = acc[b];
#pragma unroll
        for (int o = 32; o > 0; o >>= 1) v = fmaxf(v, __shfl_xor(v, o, 64));
        if (lane == 0) s_red[wid][b] = v;
    }
    __syncthreads();
#pragma unroll
    for (int b = 0; b < TB; ++b)
        m[b] = fmaxf(fmaxf(s_red[0][b], s_red[1][b]),
                     fmaxf(s_red[2][b], s_red[3][b]));

    // ---- exp + chunk sum ----
    float p[TB];
#pragma unroll
    for (int b = 0; b < TB; ++b) {
        p[b] = __expf(acc[b] - m[b]);
        float s = p[b];
#pragma unroll
        for (int o = 32; o > 0; o >>= 1) s += __shfl_xor(s, o, 64);
        if (lane == 0) s_red[wid][TB + b] = s;
    }
    s_p4[tid] = make_float4(p[0], p[1], p[2], p[3]);
    __syncthreads();
    if (tid < TB) {
        float sm = s_red[0][TB + tid] + s_red[1][TB + tid] +
                   s_red[2][TB + tid] + s_red[3][TB + tid];
        smax[ch * NB + b0 + tid] = m[tid];
        ssum[ch * NB + b0 + tid] = sm;
    }

    // ---- PV: thread owns column c, n-group g (128 n's each) ----
    const int c = tid & 127;
    const int g = tid >> 7;
    float facc[TB] = {0.f, 0.f, 0.f, 0.f};
    const float* xp = xn + (n0 + g * (NPC / 2)) * INN + c;
#pragma unroll 8
    for (int k = 0; k < NPC / 2; ++k) {
        float xv = xp[k * INN];
        float4 pv = s_p4[g * (NPC / 2) + k];
        facc[0] = fmaf(pv.x, xv, facc[0]);
        facc[1] = fmaf(pv.y, xv, facc[1]);
        facc[2] = fmaf(pv.z, xv, facc[2]);
        facc[3] = fmaf(pv.w, xv, facc[3]);
    }
#pragma unroll
    for (int b = 0; b < TB; ++b) s_part[g][b][c] = facc[b];
    __syncthreads();
    {
        int idx = tid * 2;                 // TB*INN = 512 outputs, 2/thread
        int b = idx >> 7, cc = idx & 127;
        float2 o;
        o.x = s_part[0][b][cc]     + s_part[1][b][cc];
        o.y = s_part[0][b][cc + 1] + s_part[1][b][cc + 1];
        *(float2*)&part[(ch * NB + b0 + b) * INN + cc] = o;
    }
}

// out[b][c] = sum_ch part[ch][b][c]*e^{m_ch-M} / sum_ch ssum[ch][b]*e^{m_ch-M}
__global__ __launch_bounds__(256) void combine_kernel(
    const float* __restrict__ smax, const float* __restrict__ ssum,
    const float* __restrict__ part, float* __restrict__ out)
{
    int idx = blockIdx.x * 256 + threadIdx.x;   // 512*128
    int b = idx >> 7, c = idx & 127;
    float mv[NCH];
    float M = -1e30f;
#pragma unroll
    for (int ch = 0; ch < NCH; ++ch) {
        mv[ch] = smax[ch * NB + b];
        M = fmaxf(M, mv[ch]);
    }
    float den = 0.f, num = 0.f;
#pragma unroll
    for (int ch = 0; ch < NCH; ++ch) {
        float sc = __expf(mv[ch] - M);
        den = fmaf(ssum[ch * NB + b], sc, den);
        num = fmaf(part[(ch * NB + b) * INN + c], sc, num);
    }
    out[idx] = num / den;
}

extern "C" void kernel_launch(void* const* d_in, const int* in_sizes, int n_in,
                              void* d_out, int out_size, void* d_ws, size_t ws_size,
                              hipStream_t stream) {
    const float* xo = (const float*)d_in[0];
    const float* xn = (const float*)d_in[1];
    const float* W1 = (const float*)d_in[2];
    const float* b1 = (const float*)d_in[3];
    const float* W2 = (const float*)d_in[4];
    // b2 (d_in[5]) is a uniform shift on scores -> cancels in softmax.
    float* out = (float*)d_out;

    float* pre  = (float*)d_ws;                    // 2560*64 f
    float* smax = pre + (NB + NN) * HID;           // NCH*512 f
    float* ssum = smax + NCH * NB;                 // NCH*512 f
    float* part = ssum + NCH * NB;                 // NCH*512*128 f (2 MB)

    const int total = (NB + NN) * HID;
    pre_kernel<<<(total + 255) / 256, 256, 0, stream>>>(xo, xn, W1, b1, pre);
    score_pv_kernel<<<(NB / TB) * NCH, 256, 0, stream>>>(pre, xn, W2, smax, ssum, part);
    combine_kernel<<<(NB * INN) / 256, 256, 0, stream>>>(smax, ssum, part, out);
}

// Round 7
// 140.955 us; speedup vs baseline: 1.4410x; 1.4410x over previous
//
#include <hip/hip_runtime.h>
#include <math.h>

#define INO 128
#define INN 128
#define HID 64
#define NB  512
#define NN  2048
#define TB  4            // b-rows per block
#define NCH 4            // n-chunks
#define NPC (NN / NCH)   // 512 n per chunk

// pre[row][h], rows [0,512)=xo@W1[:128]+b1, rows [512,2560)=xn@W1[128:].
__global__ __launch_bounds__(256) void pre_kernel(
    const float* __restrict__ xo, const float* __restrict__ xn,
    const float* __restrict__ W1, const float* __restrict__ b1,
    float* __restrict__ pre)
{
    int t = blockIdx.x * blockDim.x + threadIdx.x;
    int row = t >> 6;
    int h = t & 63;
    if (row >= NB + NN) return;
    const float* x;
    const float* w;
    float a0, a1 = 0.f, a2 = 0.f, a3 = 0.f;
    if (row < NB) { x = xo + row * INO;        w = W1;             a0 = b1[h]; }
    else          { x = xn + (row - NB) * INN; w = W1 + INO * HID; a0 = 0.f;  }
    const float4* x4 = (const float4*)x;
#pragma unroll
    for (int k4 = 0; k4 < INO / 4; ++k4) {
        float4 xv = x4[k4];
        int kb = k4 * 4;
        a0 = fmaf(xv.x, w[(kb + 0) * HID + h], a0);
        a1 = fmaf(xv.y, w[(kb + 1) * HID + h], a1);
        a2 = fmaf(xv.z, w[(kb + 2) * HID + h], a2);
        a3 = fmaf(xv.w, w[(kb + 3) * HID + h], a3);
    }
    pre[row * HID + h] = (a0 + a1) + (a2 + a3);
}

// One block per (b-tile of 4) x (n-chunk of 512): scores, local softmax
// stats, and PV partials. Identical memory structure to the measured-good
// 44.5us variant; only change: __launch_bounds__(256,3) caps VGPR at 168
// (was 208 -> 2 blocks/CU) to get 3 blocks/CU co-resident.
__global__ __launch_bounds__(256, 3) void score_pv_kernel(
    const float* __restrict__ pre, const float* __restrict__ xn,
    const float* __restrict__ W2,
    float* __restrict__ smax, float* __restrict__ ssum,
    float* __restrict__ part)
{
    const int bt = blockIdx.x >> 2;     // 0..127
    const int ch = blockIdx.x & 3;      // 0..3
    const int b0 = bt * TB;
    const int n0 = ch * NPC;
    const int tid = threadIdx.x;
    const int lane = tid & 63, wid = tid >> 6;

    __shared__ float  s_po[TB][HID];
    __shared__ float  s_w2[HID];
    __shared__ float4 s_p4[NPC];            // p[n_local] for 4 b's
    __shared__ float  s_red[4][2 * TB];     // per-wave max / sum
    __shared__ float  s_gacc[4][TB][INN];   // per-wave PV partials

    const float* pre_n = pre + NB * HID;
    s_po[tid >> 6][tid & 63] = pre[(b0 + (tid >> 6)) * HID + (tid & 63)];
    if (tid < HID) s_w2[tid] = W2[tid];
    __syncthreads();

    // ---- scores: thread owns n_local = tid and tid+256, all 4 b's ----
    float acc[2][TB] = {{0.f, 0.f, 0.f, 0.f}, {0.f, 0.f, 0.f, 0.f}};
    const float4* pn0 = (const float4*)(pre_n + (n0 + tid) * HID);
    const float4* pn1 = (const float4*)(pre_n + (n0 + tid + 256) * HID);
#pragma unroll
    for (int j = 0; j < HID / 4; ++j) {
        float4 v0 = pn0[j];
        float4 v1 = pn1[j];
#pragma unroll
        for (int hh = 0; hh < 4; ++hh) {
            float w = s_w2[4 * j + hh];
            float e0 = (&v0.x)[hh];
            float e1 = (&v1.x)[hh];
#pragma unroll
            for (int b = 0; b < TB; ++b) {
                float po = s_po[b][4 * j + hh];
                float t0 = po + e0;
                float t1 = po + e1;
                t0 = t0 > 0.f ? t0 : 0.2f * t0;
                t1 = t1 > 0.f ? t1 : 0.2f * t1;
                acc[0][b] = fmaf(t0, w, acc[0][b]);
                acc[1][b] = fmaf(t1, w, acc[1][b]);
            }
        }
    }

    // ---- per-b chunk max ----
    float m[TB];
#pragma unroll
    for (int b = 0; b < TB; ++b) {
        float v = fmaxf(acc[0][b], acc[1][b]);
#pragma unroll
        for (int o = 32; o > 0; o >>= 1) v = fmaxf(v, __shfl_xor(v, o, 64));
        if (lane == 0) s_red[wid][b] = v;
    }
    __syncthreads();
#pragma unroll
    for (int b = 0; b < TB; ++b)
        m[b] = fmaxf(fmaxf(s_red[0][b], s_red[1][b]),
                     fmaxf(s_red[2][b], s_red[3][b]));

    // ---- exp + chunk sum ----
    float p0[TB], p1[TB];
#pragma unroll
    for (int b = 0; b < TB; ++b) {
        p0[b] = __expf(acc[0][b] - m[b]);
        p1[b] = __expf(acc[1][b] - m[b]);
        float s = p0[b] + p1[b];
#pragma unroll
        for (int o = 32; o > 0; o >>= 1) s += __shfl_xor(s, o, 64);
        if (lane == 0) s_red[wid][TB + b] = s;
    }
    s_p4[tid]       = make_float4(p0[0], p0[1], p0[2], p0[3]);
    s_p4[tid + 256] = make_float4(p1[0], p1[1], p1[2], p1[3]);
    __syncthreads();
    if (tid < TB) {
        float sm = s_red[0][TB + tid] + s_red[1][TB + tid] +
                   s_red[2][TB + tid] + s_red[3][TB + tid];
        smax[ch * NB + b0 + tid] = m[tid];
        ssum[ch * NB + b0 + tid] = sm;
    }

    // ---- PV partials: wave w owns 128 n's; lane owns 2 columns ----
    float pacc[TB][2] = {};
    const int c0 = lane * 2;
#pragma unroll 4
    for (int k = 0; k < NPC / 4; ++k) {
        int nl = wid * (NPC / 4) + k;
        float2 xv = *(const float2*)(xn + (n0 + nl) * INN + c0);
        float4 pv = s_p4[nl];
        pacc[0][0] = fmaf(pv.x, xv.x, pacc[0][0]);
        pacc[0][1] = fmaf(pv.x, xv.y, pacc[0][1]);
        pacc[1][0] = fmaf(pv.y, xv.x, pacc[1][0]);
        pacc[1][1] = fmaf(pv.y, xv.y, pacc[1][1]);
        pacc[2][0] = fmaf(pv.z, xv.x, pacc[2][0]);
        pacc[2][1] = fmaf(pv.z, xv.y, pacc[2][1]);
        pacc[3][0] = fmaf(pv.w, xv.x, pacc[3][0]);
        pacc[3][1] = fmaf(pv.w, xv.y, pacc[3][1]);
    }
#pragma unroll
    for (int b = 0; b < TB; ++b) {
        s_gacc[wid][b][c0]     = pacc[b][0];
        s_gacc[wid][b][c0 + 1] = pacc[b][1];
    }
    __syncthreads();
#pragma unroll
    for (int t = 0; t < 2; ++t) {
        int idx = tid * 2 + t;
        int b = idx >> 7, c = idx & 127;
        float s = s_gacc[0][b][c] + s_gacc[1][b][c] +
                  s_gacc[2][b][c] + s_gacc[3][b][c];
        part[(ch * NB + b0 + b) * INN + c] = s;
    }
}

// out[b][c] = sum_ch part[ch][b][c]*e^{m_ch-M} / sum_ch ssum[ch][b]*e^{m_ch-M}
__global__ __launch_bounds__(256) void combine_kernel(
    const float* __restrict__ smax, const float* __restrict__ ssum,
    const float* __restrict__ part, float* __restrict__ out)
{
    int idx = blockIdx.x * 256 + threadIdx.x;   // 512*128
    int b = idx >> 7, c = idx & 127;
    float mv[NCH];
    float M = -1e30f;
#pragma unroll
    for (int ch = 0; ch < NCH; ++ch) {
        mv[ch] = smax[ch * NB + b];
        M = fmaxf(M, mv[ch]);
    }
    float den = 0.f, num = 0.f;
#pragma unroll
    for (int ch = 0; ch < NCH; ++ch) {
        float sc = __expf(mv[ch] - M);
        den = fmaf(ssum[ch * NB + b], sc, den);
        num = fmaf(part[(ch * NB + b) * INN + c], sc, num);
    }
    out[idx] = num / den;
}

extern "C" void kernel_launch(void* const* d_in, const int* in_sizes, int n_in,
                              void* d_out, int out_size, void* d_ws, size_t ws_size,
                              hipStream_t stream) {
    const float* xo = (const float*)d_in[0];
    const float* xn = (const float*)d_in[1];
    const float* W1 = (const float*)d_in[2];
    const float* b1 = (const float*)d_in[3];
    const float* W2 = (const float*)d_in[4];
    // b2 (d_in[5]) is a uniform shift on scores -> cancels in softmax.
    float* out = (float*)d_out;

    float* pre  = (float*)d_ws;                    // 2560*64 f
    float* smax = pre + (NB + NN) * HID;           // NCH*512 f
    float* ssum = smax + NCH * NB;                 // NCH*512 f
    float* part = ssum + NCH * NB;                 // NCH*512*128 f (1 MB)

    const int total = (NB + NN) * HID;
    pre_kernel<<<(total + 255) / 256, 256, 0, stream>>>(xo, xn, W1, b1, pre);
    score_pv_kernel<<<(NB / TB) * NCH, 256, 0, stream>>>(pre, xn, W2, smax, ssum, part);
    combine_kernel<<<(NB * INN) / 256, 256, 0, stream>>>(smax, ssum, part, out);
}

// Round 8
// 93.804 us; speedup vs baseline: 2.1654x; 1.5027x over previous
//
#include <hip/hip_runtime.h>
#include <math.h>

#define INO 128
#define INN 128
#define HID 64
#define NB  512
#define NN  2048
#define TB  4            // b-rows per block
#define NCH 8            // n-chunks
#define NPC (NN / NCH)   // 256 n per chunk

// pre[row][h], rows [0,512)=xo@W1[:128]+b1, rows [512,2560)=xn@W1[128:].
__global__ __launch_bounds__(256) void pre_kernel(
    const float* __restrict__ xo, const float* __restrict__ xn,
    const float* __restrict__ W1, const float* __restrict__ b1,
    float* __restrict__ pre)
{
    int t = blockIdx.x * blockDim.x + threadIdx.x;
    int row = t >> 6;
    int h = t & 63;
    if (row >= NB + NN) return;
    const float* x;
    const float* w;
    float a0, a1 = 0.f, a2 = 0.f, a3 = 0.f;
    if (row < NB) { x = xo + row * INO;        w = W1;             a0 = b1[h]; }
    else          { x = xn + (row - NB) * INN; w = W1 + INO * HID; a0 = 0.f;  }
    const float4* x4 = (const float4*)x;
#pragma unroll
    for (int k4 = 0; k4 < INO / 4; ++k4) {
        float4 xv = x4[k4];
        int kb = k4 * 4;
        a0 = fmaf(xv.x, w[(kb + 0) * HID + h], a0);
        a1 = fmaf(xv.y, w[(kb + 1) * HID + h], a1);
        a2 = fmaf(xv.z, w[(kb + 2) * HID + h], a2);
        a3 = fmaf(xv.w, w[(kb + 3) * HID + h], a3);
    }
    pre[row * HID + h] = (a0 + a1) + (a2 + a3);
}

// One block per (b-tile of 4) x (n-chunk of 256). One n per thread in the
// score phase; #pragma unroll 4 caps in-flight float4 loads at 4 so the
// natural VGPR count stays low. NO min-waves launch bound: R6/R7 showed the
// bound forces ~1KB/thread scratch spill (FETCH/WRITE ~100-200MB symmetric).
__global__ __launch_bounds__(256) void score_pv_kernel(
    const float* __restrict__ pre, const float* __restrict__ xn,
    const float* __restrict__ W2,
    float* __restrict__ smax, float* __restrict__ ssum,
    float* __restrict__ part)
{
    const int bt = blockIdx.x >> 3;     // 0..127
    const int ch = blockIdx.x & 7;      // 0..7
    const int b0 = bt * TB;
    const int n0 = ch * NPC;
    const int tid = threadIdx.x;
    const int lane = tid & 63, wid = tid >> 6;

    __shared__ float  s_po[TB][HID];       // 1 KB
    __shared__ float  s_w2[HID];           // 256 B
    __shared__ float4 s_p4[NPC];           // 4 KB: p[n_local] for 4 b's
    __shared__ float  s_red[4][2 * TB];    // per-wave max / sum
    __shared__ float  s_part[2][TB][INN];  // 4 KB: PV partials (2 n-groups)

    const float* pre_n = pre + NB * HID;
    s_po[tid >> 6][tid & 63] = pre[(b0 + (tid >> 6)) * HID + (tid & 63)];
    if (tid < HID) s_w2[tid] = W2[tid];
    __syncthreads();

    // ---- scores: thread owns n_local = tid, all 4 b's ----
    float acc[TB] = {0.f, 0.f, 0.f, 0.f};
    const float4* pn = (const float4*)(pre_n + (n0 + tid) * HID);
#pragma unroll 4
    for (int j = 0; j < HID / 4; ++j) {
        float4 v = pn[j];
#pragma unroll
        for (int hh = 0; hh < 4; ++hh) {
            float w = s_w2[4 * j + hh];
            float e = (&v.x)[hh];
#pragma unroll
            for (int b = 0; b < TB; ++b) {
                float t = s_po[b][4 * j + hh] + e;
                acc[b] = fmaf(fmaxf(t, 0.2f * t), w, acc[b]);
            }
        }
    }

    // ---- per-b chunk max ----
    float m[TB];
#pragma unroll
    for (int b = 0; b < TB; ++b) {
        float v = acc[b];
#pragma unroll
        for (int o = 32; o > 0; o >>= 1) v = fmaxf(v, __shfl_xor(v, o, 64));
        if (lane == 0) s_red[wid][b] = v;
    }
    __syncthreads();
#pragma unroll
    for (int b = 0; b < TB; ++b)
        m[b] = fmaxf(fmaxf(s_red[0][b], s_red[1][b]),
                     fmaxf(s_red[2][b], s_red[3][b]));

    // ---- exp + chunk sum ----
    float p[TB];
#pragma unroll
    for (int b = 0; b < TB; ++b) {
        p[b] = __expf(acc[b] - m[b]);
        float s = p[b];
#pragma unroll
        for (int o = 32; o > 0; o >>= 1) s += __shfl_xor(s, o, 64);
        if (lane == 0) s_red[wid][TB + b] = s;
    }
    s_p4[tid] = make_float4(p[0], p[1], p[2], p[3]);
    __syncthreads();
    if (tid < TB) {
        float sm = s_red[0][TB + tid] + s_red[1][TB + tid] +
                   s_red[2][TB + tid] + s_red[3][TB + tid];
        smax[ch * NB + b0 + tid] = m[tid];
        ssum[ch * NB + b0 + tid] = sm;
    }

    // ---- PV: thread owns column c, n-group g (128 n's each) ----
    const int c = tid & 127;
    const int g = tid >> 7;
    float facc[TB] = {0.f, 0.f, 0.f, 0.f};
    const float* xp = xn + (n0 + g * (NPC / 2)) * INN + c;
#pragma unroll 8
    for (int k = 0; k < NPC / 2; ++k) {
        float xv = xp[k * INN];
        float4 pv = s_p4[g * (NPC / 2) + k];
        facc[0] = fmaf(pv.x, xv, facc[0]);
        facc[1] = fmaf(pv.y, xv, facc[1]);
        facc[2] = fmaf(pv.z, xv, facc[2]);
        facc[3] = fmaf(pv.w, xv, facc[3]);
    }
#pragma unroll
    for (int b = 0; b < TB; ++b) s_part[g][b][c] = facc[b];
    __syncthreads();
    {
        int idx = tid * 2;                 // TB*INN = 512 outputs, 2/thread
        int b = idx >> 7, cc = idx & 127;
        float2 o;
        o.x = s_part[0][b][cc]     + s_part[1][b][cc];
        o.y = s_part[0][b][cc + 1] + s_part[1][b][cc + 1];
        *(float2*)&part[(ch * NB + b0 + b) * INN + cc] = o;
    }
}

// out[b][c] = sum_ch part[ch][b][c]*e^{m_ch-M} / sum_ch ssum[ch][b]*e^{m_ch-M}
__global__ __launch_bounds__(256) void combine_kernel(
    const float* __restrict__ smax, const float* __restrict__ ssum,
    const float* __restrict__ part, float* __restrict__ out)
{
    int idx = blockIdx.x * 256 + threadIdx.x;   // 512*128
    int b = idx >> 7, c = idx & 127;
    float mv[NCH];
    float M = -1e30f;
#pragma unroll
    for (int ch = 0; ch < NCH; ++ch) {
        mv[ch] = smax[ch * NB + b];
        M = fmaxf(M, mv[ch]);
    }
    float den = 0.f, num = 0.f;
#pragma unroll
    for (int ch = 0; ch < NCH; ++ch) {
        float sc = __expf(mv[ch] - M);
        den = fmaf(ssum[ch * NB + b], sc, den);
        num = fmaf(part[(ch * NB + b) * INN + c], sc, num);
    }
    out[idx] = num / den;
}

extern "C" void kernel_launch(void* const* d_in, const int* in_sizes, int n_in,
                              void* d_out, int out_size, void* d_ws, size_t ws_size,
                              hipStream_t stream) {
    const float* xo = (const float*)d_in[0];
    const float* xn = (const float*)d_in[1];
    const float* W1 = (const float*)d_in[2];
    const float* b1 = (const float*)d_in[3];
    const float* W2 = (const float*)d_in[4];
    // b2 (d_in[5]) is a uniform shift on scores -> cancels in softmax.
    float* out = (float*)d_out;

    float* pre  = (float*)d_ws;                    // 2560*64 f
    float* smax = pre + (NB + NN) * HID;           // NCH*512 f
    float* ssum = smax + NCH * NB;                 // NCH*512 f
    float* part = ssum + NCH * NB;                 // NCH*512*128 f (2 MB)

    const int total = (NB + NN) * HID;
    pre_kernel<<<(total + 255) / 256, 256, 0, stream>>>(xo, xn, W1, b1, pre);
    score_pv_kernel<<<(NB / TB) * NCH, 256, 0, stream>>>(pre, xn, W2, smax, ssum, part);
    combine_kernel<<<(NB * INN) / 256, 256, 0, stream>>>(smax, ssum, part, out);
}

// Round 12
// 87.610 us; speedup vs baseline: 2.3185x; 1.0707x over previous
//
#include <hip/hip_runtime.h>
#include <math.h>

#define INO 128
#define INN 128
#define HID 64
#define NB  512
#define NN  2048
#define TB  4            // b-rows per block
#define NCH 8            // n-chunks
#define NPC (NN / NCH)   // 256 n per chunk

// pre[row][h], rows [0,512)=xo@W1[:128]+b1, rows [512,2560)=xn@W1[128:].
__global__ __launch_bounds__(256) void pre_kernel(
    const float* __restrict__ xo, const float* __restrict__ xn,
    const float* __restrict__ W1, const float* __restrict__ b1,
    float* __restrict__ pre)
{
    int t = blockIdx.x * blockDim.x + threadIdx.x;
    int row = t >> 6;
    int h = t & 63;
    if (row >= NB + NN) return;
    const float* x;
    const float* w;
    float a0, a1 = 0.f, a2 = 0.f, a3 = 0.f;
    if (row < NB) { x = xo + row * INO;        w = W1;             a0 = b1[h]; }
    else          { x = xn + (row - NB) * INN; w = W1 + INO * HID; a0 = 0.f;  }
    const float4* x4 = (const float4*)x;
#pragma unroll
    for (int k4 = 0; k4 < INO / 4; ++k4) {
        float4 xv = x4[k4];
        int kb = k4 * 4;
        a0 = fmaf(xv.x, w[(kb + 0) * HID + h], a0);
        a1 = fmaf(xv.y, w[(kb + 1) * HID + h], a1);
        a2 = fmaf(xv.z, w[(kb + 2) * HID + h], a2);
        a3 = fmaf(xv.w, w[(kb + 3) * HID + h], a3);
    }
    pre[row * HID + h] = (a0 + a1) + (a2 + a3);
}

// One block per (b-tile of 4) x (n-chunk of 256).
// Score phase: po/W2 read via WAVE-UNIFORM global indices -> compiler emits
// scalar s_load (K$), eliminating the 320 LDS reads/thread of the R8 version.
// PV phase: thread owns a float4 column slice and a 32-n group (8 groups),
// cutting LDS reads to 32 b128/thread. No min-waves bound (R6/R7: forces spill).
__global__ __launch_bounds__(256) void score_pv_kernel(
    const float* __restrict__ pre, const float* __restrict__ xn,
    const float* __restrict__ W2,
    float* __restrict__ smax, float* __restrict__ ssum,
    float* __restrict__ part)
{
    const int bt = blockIdx.x >> 3;     // 0..127
    const int ch = blockIdx.x & 7;      // 0..7
    const int b0 = bt * TB;
    const int n0 = ch * NPC;
    const int tid = threadIdx.x;
    const int lane = tid & 63, wid = tid >> 6;

    __shared__ float4 s_p4[NPC];               // 4 KB: p[n_local] for 4 b's
    __shared__ float  s_red[4][2 * TB];        // per-wave max / sum
    __shared__ float4 s_part4[8][TB][INN / 4]; // 16 KB: PV partials (8 n-groups)

    const float* pre_n = pre + NB * HID;
    const float* po = pre + b0 * HID;   // uniform base for scalar loads

    // ---- scores: thread owns n_local = tid, all 4 b's ----
    float acc[TB] = {0.f, 0.f, 0.f, 0.f};
    const float4* pn = (const float4*)(pre_n + (n0 + tid) * HID);
#pragma unroll 4
    for (int j = 0; j < HID / 4; ++j) {
        float4 v = pn[j];
#pragma unroll
        for (int hh = 0; hh < 4; ++hh) {
            const int h = 4 * j + hh;
            const float w = W2[h];            // uniform -> s_load
            const float e = (&v.x)[hh];
#pragma unroll
            for (int b = 0; b < TB; ++b) {
                float t = po[b * HID + h] + e;  // uniform -> s_load
                acc[b] = fmaf(fmaxf(t, 0.2f * t), w, acc[b]);
            }
        }
    }

    // ---- per-b chunk max ----
    float m[TB];
#pragma unroll
    for (int b = 0; b < TB; ++b) {
        float v = acc[b];
#pragma unroll
        for (int o = 32; o > 0; o >>= 1) v = fmaxf(v, __shfl_xor(v, o, 64));
        if (lane == 0) s_red[wid][b] = v;
    }
    __syncthreads();
#pragma unroll
    for (int b = 0; b < TB; ++b)
        m[b] = fmaxf(fmaxf(s_red[0][b], s_red[1][b]),
                     fmaxf(s_red[2][b], s_red[3][b]));

    // ---- exp + chunk sum ----
    float p[TB];
#pragma unroll
    for (int b = 0; b < TB; ++b) {
        p[b] = __expf(acc[b] - m[b]);
        float s = p[b];
#pragma unroll
        for (int o = 32; o > 0; o >>= 1) s += __shfl_xor(s, o, 64);
        if (lane == 0) s_red[wid][TB + b] = s;
    }
    s_p4[tid] = make_float4(p[0], p[1], p[2], p[3]);
    __syncthreads();
    if (tid < TB) {
        float sm = s_red[0][TB + tid] + s_red[1][TB + tid] +
                   s_red[2][TB + tid] + s_red[3][TB + tid];
        smax[ch * NB + b0 + tid] = m[tid];
        ssum[ch * NB + b0 + tid] = sm;
    }

    // ---- PV: thread owns float4 cols [4*c4, 4*c4+4), n-group g (32 n's) ----
    const int c4 = tid & 31;
    const int g  = tid >> 5;
    float4 f[TB];
#pragma unroll
    for (int b = 0; b < TB; ++b) f[b] = make_float4(0.f, 0.f, 0.f, 0.f);
    const float* xp = xn + (size_t)(n0 + g * 32) * INN + c4 * 4;
#pragma unroll 8
    for (int k = 0; k < 32; ++k) {
        float4 xv = *(const float4*)(xp + (size_t)k * INN);
        float4 pv = s_p4[g * 32 + k];
        f[0].x = fmaf(pv.x, xv.x, f[0].x);
        f[0].y = fmaf(pv.x, xv.y, f[0].y);
        f[0].z = fmaf(pv.x, xv.z, f[0].z);
        f[0].w = fmaf(pv.x, xv.w, f[0].w);
        f[1].x = fmaf(pv.y, xv.x, f[1].x);
        f[1].y = fmaf(pv.y, xv.y, f[1].y);
        f[1].z = fmaf(pv.y, xv.z, f[1].z);
        f[1].w = fmaf(pv.y, xv.w, f[1].w);
        f[2].x = fmaf(pv.z, xv.x, f[2].x);
        f[2].y = fmaf(pv.z, xv.y, f[2].y);
        f[2].z = fmaf(pv.z, xv.z, f[2].z);
        f[2].w = fmaf(pv.z, xv.w, f[2].w);
        f[3].x = fmaf(pv.w, xv.x, f[3].x);
        f[3].y = fmaf(pv.w, xv.y, f[3].y);
        f[3].z = fmaf(pv.w, xv.z, f[3].z);
        f[3].w = fmaf(pv.w, xv.w, f[3].w);
    }
#pragma unroll
    for (int b = 0; b < TB; ++b) s_part4[g][b][c4] = f[b];
    __syncthreads();
    if (tid < TB * (INN / 4)) {         // 128 threads: b = tid>>5, c4 = tid&31
        int b = tid >> 5, cc = tid & 31;
        float4 s = make_float4(0.f, 0.f, 0.f, 0.f);
#pragma unroll
        for (int gg = 0; gg < 8; ++gg) {
            float4 v = s_part4[gg][b][cc];
            s.x += v.x; s.y += v.y; s.z += v.z; s.w += v.w;
        }
        *(float4*)&part[(size_t)(ch * NB + b0 + b) * INN + cc * 4] = s;
    }
}

// out[b][c] = sum_ch part[ch][b][c]*e^{m_ch-M} / sum_ch ssum[ch][b]*e^{m_ch-M}
__global__ __launch_bounds__(256) void combine_kernel(
    const float* __restrict__ smax, const float* __restrict__ ssum,
    const float* __restrict__ part, float* __restrict__ out)
{
    int idx = blockIdx.x * 256 + threadIdx.x;   // 512*128
    int b = idx >> 7, c = idx & 127;
    float mv[NCH];
    float M = -1e30f;
#pragma unroll
    for (int ch = 0; ch < NCH; ++ch) {
        mv[ch] = smax[ch * NB + b];
        M = fmaxf(M, mv[ch]);
    }
    float den = 0.f, num = 0.f;
#pragma unroll
    for (int ch = 0; ch < NCH; ++ch) {
        float sc = __expf(mv[ch] - M);
        den = fmaf(ssum[ch * NB + b], sc, den);
        num = fmaf(part[(size_t)(ch * NB + b) * INN + c], sc, num);
    }
    out[idx] = num / den;
}

extern "C" void kernel_launch(void* const* d_in, const int* in_sizes, int n_in,
                              void* d_out, int out_size, void* d_ws, size_t ws_size,
                              hipStream_t stream) {
    const float* xo = (const float*)d_in[0];
    const float* xn = (const float*)d_in[1];
    const float* W1 = (const float*)d_in[2];
    const float* b1 = (const float*)d_in[3];
    const float* W2 = (const float*)d_in[4];
    // b2 (d_in[5]) is a uniform shift on scores -> cancels in softmax.
    float* out = (float*)d_out;

    float* pre  = (float*)d_ws;                    // 2560*64 f
    float* smax = pre + (NB + NN) * HID;           // 8*512 f
    float* ssum = smax + NCH * NB;                 // 8*512 f
    float* part = ssum + NCH * NB;                 // 8*512*128 f (2 MB)

    const int total = (NB + NN) * HID;
    pre_kernel<<<(total + 255) / 256, 256, 0, stream>>>(xo, xn, W1, b1, pre);
    score_pv_kernel<<<(NB / TB) * NCH, 256, 0, stream>>>(pre, xn, W2, smax, ssum, part);
    combine_kernel<<<(NB * INN) / 256, 256, 0, stream>>>(smax, ssum, part, out);
}